// Round 1
// baseline (329.919 us; speedup 1.0000x reference)
//
#include <hip/hip_runtime.h>
#include <stdint.h>

typedef __bf16 bf16x8 __attribute__((ext_vector_type(8)));
typedef float f32x4 __attribute__((ext_vector_type(4)));

#define B_ 16
#define C_ 512
#define S_ 1024   // W*H = 32*32
#define N1 1536   // 3C

// ---------- bf16 helpers (manual RNE, no NaN inputs expected) ----------
__device__ inline unsigned short f2b(float f) {
    unsigned int u = __builtin_bit_cast(unsigned int, f);
    unsigned int lsb = (u >> 16) & 1u;
    u += 0x7fffu + lsb;
    return (unsigned short)(u >> 16);
}
__device__ inline float b2f(unsigned int s) {
    unsigned int u = (s & 0xffffu) << 16;
    return __builtin_bit_cast(float, u);
}

// ---------- prep: x (B,C,S) f32 -> xT (B,S,C) bf16 ----------
__global__ void transpose_convert_x(const float* __restrict__ x, unsigned short* __restrict__ xT) {
    __shared__ float tile[32][33];
    int b = blockIdx.z;
    int c0 = blockIdx.y * 32;
    int s0 = blockIdx.x * 32;
    int tx = threadIdx.x, ty = threadIdx.y; // (32,8)
    const float* xp = x + ((size_t)b * C_ + c0) * S_ + s0;
#pragma unroll
    for (int i = 0; i < 4; i++)
        tile[ty + i * 8][tx] = xp[(size_t)(ty + i * 8) * S_ + tx];
    __syncthreads();
    unsigned short* op = xT + ((size_t)b * S_ + s0) * C_ + c0;
#pragma unroll
    for (int i = 0; i < 4; i++)
        op[(size_t)(ty + i * 8) * C_ + tx] = f2b(tile[tx][ty + i * 8]);
}

// ---------- prep: f32 -> bf16 (vector x4) ----------
__global__ void convert_f32_bf16(const float* __restrict__ src, unsigned short* __restrict__ dst, int n4) {
    int i = blockIdx.x * blockDim.x + threadIdx.x;
    if (i < n4) {
        float4 v = ((const float4*)src)[i];
        ((ushort4*)dst)[i] = make_ushort4(f2b(v.x), f2b(v.y), f2b(v.z), f2b(v.w));
    }
}

// ---------- zero fill ----------
__global__ void zero_f32(float* __restrict__ p, int n) {
    int i = blockIdx.x * blockDim.x + threadIdx.x;
    if (i < n) p[i] = 0.0f;
}

// ---------- GEMM: C[m,n] = A[m,:] . Wt[n,:] + bias[n] ----------
// A: MxK bf16 row-major (K contig), Wt: NxK bf16 row-major. K=512.
// TRANS_OUT=false: store bf16 y[m*N + n]
// TRANS_OUT=true : store f32 out[(b*512+n)*1024 + s], m = b*1024+s  (N must be 512)
template <bool TRANS_OUT>
__global__ __launch_bounds__(256) void gemm_bf16(
    const unsigned short* __restrict__ A,
    const unsigned short* __restrict__ Wt,
    const float* __restrict__ bias,
    void* __restrict__ Cout,
    int N)
{
    const int K = 512;
    __shared__ __align__(16) unsigned short As[128 * 40]; // 80B row stride (pad)
    __shared__ __align__(16) unsigned short Bs[128 * 40];
    int m0 = blockIdx.x * 128;
    int n0 = blockIdx.y * 128;
    int tid = threadIdx.x;
    int lane = tid & 63, wid = tid >> 6;
    int wm = (wid >> 1) * 64, wn = (wid & 1) * 64;
    int quad = lane >> 4, l16 = lane & 15;

    f32x4 acc[4][4] = {};

    for (int kt = 0; kt < K; kt += 32) {
        __syncthreads();
#pragma unroll
        for (int r = 0; r < 2; r++) {
            int ch = tid + r * 256;       // 512 chunks of 16B per tile
            int m = ch >> 2, kc = ch & 3;
            *(uint4*)(&As[m * 40 + kc * 8]) = *(const uint4*)(&A[(size_t)(m0 + m) * K + kt + kc * 8]);
            *(uint4*)(&Bs[m * 40 + kc * 8]) = *(const uint4*)(&Wt[(size_t)(n0 + m) * K + kt + kc * 8]);
        }
        __syncthreads();
        bf16x8 af[4], bf[4];
#pragma unroll
        for (int t = 0; t < 4; t++) {
            af[t] = *(const bf16x8*)(&As[(wm + t * 16 + l16) * 40 + quad * 8]);
            bf[t] = *(const bf16x8*)(&Bs[(wn + t * 16 + l16) * 40 + quad * 8]);
        }
#pragma unroll
        for (int mt = 0; mt < 4; mt++)
#pragma unroll
            for (int nt = 0; nt < 4; nt++)
                acc[mt][nt] = __builtin_amdgcn_mfma_f32_16x16x32_bf16(af[mt], bf[nt], acc[mt][nt], 0, 0, 0);
    }

#pragma unroll
    for (int mt = 0; mt < 4; mt++) {
#pragma unroll
        for (int nt = 0; nt < 4; nt++) {
            int n = n0 + wn + nt * 16 + l16;
            float bv = bias[n];
            int mbase = m0 + wm + mt * 16 + quad * 4;
            if (!TRANS_OUT) {
                unsigned short* Y = (unsigned short*)Cout;
#pragma unroll
                for (int r = 0; r < 4; r++)
                    Y[(size_t)(mbase + r) * N + n] = f2b(acc[mt][nt][r] + bv);
            } else {
                float* Z = (float*)Cout;
                int b = mbase >> 10;
                int s = mbase & 1023;
                float4 v = make_float4(acc[mt][nt][0] + bv, acc[mt][nt][1] + bv,
                                       acc[mt][nt][2] + bv, acc[mt][nt][3] + bv);
                *(float4*)(&Z[((size_t)(b * 512 + n)) * 1024 + s]) = v;
            }
        }
    }
}

// shift tables per quarter q = c>>7:
// x1: dw = {-1,+1,0,0}[q], dh = {0,0,-1,+1}[q]   (channels [0,512) of y)
// x2: dh = {-1,+1,0,0}[q], dw = {0,0,-1,+1}[q]   (channels [512,1024))
// x3: no shift                                    (channels [1024,1536))

// ---------- a[b,c] = sum_{w,h} (x1+x2+x3) ----------
__global__ void asum_kernel(const unsigned short* __restrict__ y, float* __restrict__ a) {
    int b = blockIdx.y;
    int w0 = blockIdx.x * 2;
    int t = threadIdx.x;
    int c = t * 2;
    int q = c >> 7;
    int dw1 = (q == 0) ? -1 : (q == 1) ? 1 : 0;
    int dh1 = (q == 2) ? -1 : (q == 3) ? 1 : 0;
    int dh2 = (q == 0) ? -1 : (q == 1) ? 1 : 0;
    int dw2 = (q == 2) ? -1 : (q == 3) ? 1 : 0;
    float s0 = 0.f, s1 = 0.f;
    size_t base = (size_t)b * S_;
    for (int p = 0; p < 64; p++) {
        int w = w0 + (p >> 5);
        int h = p & 31;
        int w1i = min(max(w + dw1, 0), 31), h1i = min(max(h + dh1, 0), 31);
        int w2i = min(max(w + dw2, 0), 31), h2i = min(max(h + dh2, 0), 31);
        unsigned int v1 = *(const unsigned int*)&y[(base + w1i * 32 + h1i) * N1 + c];
        unsigned int v2 = *(const unsigned int*)&y[(base + w2i * 32 + h2i) * N1 + 512 + c];
        unsigned int v3 = *(const unsigned int*)&y[(base + w * 32 + h) * N1 + 1024 + c];
        s0 += b2f(v1) + b2f(v2) + b2f(v3);
        s1 += b2f(v1 >> 16) + b2f(v2 >> 16) + b2f(v3 >> 16);
    }
    atomicAdd(&a[b * 512 + c], s0);
    atomicAdd(&a[b * 512 + c + 1], s1);
}

// ---------- gating MLP + softmax: g[b,3,512] ----------
__global__ __launch_bounds__(256) void mlp_gate_kernel(
    const float* __restrict__ a,
    const float* __restrict__ wa, const float* __restrict__ ba,
    const float* __restrict__ wb, const float* __restrict__ bb,
    float* __restrict__ g)
{
    __shared__ __align__(16) float sa[512];
    __shared__ __align__(16) float sh[512];
    __shared__ __align__(16) float shat[1536];
    int b = blockIdx.x;
    int t = threadIdx.x;
    sa[t] = a[b * 512 + t];
    sa[t + 256] = a[b * 512 + t + 256];
    __syncthreads();
#pragma unroll
    for (int r = 0; r < 2; r++) {
        int o = t + r * 256;
        const float4* wr = (const float4*)(&wa[(size_t)o * 512]);
        float dot = 0.f;
        for (int k = 0; k < 128; k++) {
            float4 wv = wr[k];
            float4 av = ((const float4*)sa)[k];
            dot += wv.x * av.x + wv.y * av.y + wv.z * av.z + wv.w * av.w;
        }
        float v = dot + ba[o];
        sh[o] = 0.5f * v * (1.0f + erff(v * 0.7071067811865475f)); // exact gelu
    }
    __syncthreads();
#pragma unroll
    for (int r = 0; r < 6; r++) {
        int o = t + r * 256;
        const float4* wr = (const float4*)(&wb[(size_t)o * 512]);
        float dot = 0.f;
        for (int k = 0; k < 128; k++) {
            float4 wv = wr[k];
            float4 hv = ((const float4*)sh)[k];
            dot += wv.x * hv.x + wv.y * hv.y + wv.z * hv.z + wv.w * hv.w;
        }
        shat[o] = dot + bb[o];
    }
    __syncthreads();
#pragma unroll
    for (int r = 0; r < 2; r++) {
        int c = t + r * 256;
        float h0 = shat[c], h1 = shat[c + 512], h2 = shat[c + 1024];
        float mx = fmaxf(h0, fmaxf(h1, h2));
        float e0 = __expf(h0 - mx), e1 = __expf(h1 - mx), e2 = __expf(h2 - mx);
        float inv = 1.0f / (e0 + e1 + e2);
        g[(b * 3 + 0) * 512 + c] = e0 * inv;
        g[(b * 3 + 1) * 512 + c] = e1 * inv;
        g[(b * 3 + 2) * 512 + c] = e2 * inv;
    }
}

// ---------- out[b,s,c] = g0*x1 + g1*x2 + g2*x3 (bf16) ----------
__global__ void combine_kernel(const unsigned short* __restrict__ y,
                               const float* __restrict__ g,
                               unsigned short* __restrict__ outT)
{
    int b = blockIdx.y;
    int w = blockIdx.x;
    int t = threadIdx.x;
    int c = t * 2;
    int q = c >> 7;
    int dw1 = (q == 0) ? -1 : (q == 1) ? 1 : 0;
    int dh1 = (q == 2) ? -1 : (q == 3) ? 1 : 0;
    int dh2 = (q == 0) ? -1 : (q == 1) ? 1 : 0;
    int dw2 = (q == 2) ? -1 : (q == 3) ? 1 : 0;
    float g00 = g[(b * 3 + 0) * 512 + c], g01 = g[(b * 3 + 0) * 512 + c + 1];
    float g10 = g[(b * 3 + 1) * 512 + c], g11 = g[(b * 3 + 1) * 512 + c + 1];
    float g20 = g[(b * 3 + 2) * 512 + c], g21 = g[(b * 3 + 2) * 512 + c + 1];
    int w1i = min(max(w + dw1, 0), 31);
    int w2i = min(max(w + dw2, 0), 31);
    size_t base = (size_t)b * S_;
    for (int h = 0; h < 32; h++) {
        int h1i = min(max(h + dh1, 0), 31);
        int h2i = min(max(h + dh2, 0), 31);
        unsigned int v1 = *(const unsigned int*)&y[(base + w1i * 32 + h1i) * N1 + c];
        unsigned int v2 = *(const unsigned int*)&y[(base + w2i * 32 + h2i) * N1 + 512 + c];
        unsigned int v3 = *(const unsigned int*)&y[(base + w * 32 + h) * N1 + 1024 + c];
        float o0 = g00 * b2f(v1) + g10 * b2f(v2) + g20 * b2f(v3);
        float o1 = g01 * b2f(v1 >> 16) + g11 * b2f(v2 >> 16) + g21 * b2f(v3 >> 16);
        unsigned int ov = (unsigned int)f2b(o0) | ((unsigned int)f2b(o1) << 16);
        *(unsigned int*)&outT[(base + w * 32 + h) * 512 + c] = ov;
    }
}

extern "C" void kernel_launch(void* const* d_in, const int* in_sizes, int n_in,
                              void* d_out, int out_size, void* d_ws, size_t ws_size,
                              hipStream_t stream) {
    const float* x  = (const float*)d_in[0];
    const float* w1 = (const float*)d_in[1];
    const float* b1 = (const float*)d_in[2];
    const float* wa = (const float*)d_in[3];
    const float* ba = (const float*)d_in[4];
    const float* wb = (const float*)d_in[5];
    const float* bb = (const float*)d_in[6];
    const float* w2 = (const float*)d_in[7];
    const float* b2 = (const float*)d_in[8];
    float* out = (float*)d_out;

    char* ws = (char*)d_ws;
    unsigned short* xT   = (unsigned short*)(ws);              // 16 MB: (B,S,C) bf16
    unsigned short* w1b  = (unsigned short*)(ws + 16777216);   // 1.5 MB
    unsigned short* w2b  = (unsigned short*)(ws + 18350080);   // 0.5 MB
    unsigned short* y    = (unsigned short*)(ws + 18874368);   // 48 MB: (B,S,3C) bf16
    float* a_buf         = (float*)(ws + 69206016);            // 32 KB
    float* g_buf         = (float*)(ws + 69238784);            // 96 KB
    unsigned short* outT = (unsigned short*)(ws + 69337088);   // 16 MB: (B,S,C) bf16

    transpose_convert_x<<<dim3(32, 16, 16), dim3(32, 8), 0, stream>>>(x, xT);
    convert_f32_bf16<<<dim3(768), dim3(256), 0, stream>>>(w1, w1b, 196608);
    convert_f32_bf16<<<dim3(256), dim3(256), 0, stream>>>(w2, w2b, 65536);
    gemm_bf16<false><<<dim3(128, 12), dim3(256), 0, stream>>>(xT, w1b, b1, (void*)y, 1536);
    zero_f32<<<dim3(32), dim3(256), 0, stream>>>(a_buf, 8192);
    asum_kernel<<<dim3(16, 16), dim3(256), 0, stream>>>(y, a_buf);
    mlp_gate_kernel<<<dim3(16), dim3(256), 0, stream>>>(a_buf, wa, ba, wb, bb, g_buf);
    combine_kernel<<<dim3(32, 16), dim3(256), 0, stream>>>(y, g_buf, outT);
    gemm_bf16<true><<<dim3(128, 4), dim3(256), 0, stream>>>(outT, w2b, b2, (void*)out, 512);
}

// Round 2
// 217.499 us; speedup vs baseline: 1.5169x; 1.5169x over previous
//
#include <hip/hip_runtime.h>
#include <stdint.h>

typedef __bf16 bf16x8 __attribute__((ext_vector_type(8)));
typedef float f32x4 __attribute__((ext_vector_type(4)));

#define B_ 16
#define C_ 512
#define S_ 1024   // W*H = 32*32
#define N1 1536   // 3C

// ---------- bf16 helpers (manual RNE, no NaN inputs expected) ----------
__device__ inline unsigned short f2b(float f) {
    unsigned int u = __builtin_bit_cast(unsigned int, f);
    unsigned int lsb = (u >> 16) & 1u;
    u += 0x7fffu + lsb;
    return (unsigned short)(u >> 16);
}
__device__ inline float b2f(unsigned int s) {
    unsigned int u = (s & 0xffffu) << 16;
    return __builtin_bit_cast(float, u);
}

// ---------- prep: x (B,C,S) f32 -> xT (B,S,C) bf16 ----------
__global__ void transpose_convert_x(const float* __restrict__ x, unsigned short* __restrict__ xT) {
    __shared__ float tile[32][33];
    int b = blockIdx.z;
    int c0 = blockIdx.y * 32;
    int s0 = blockIdx.x * 32;
    int tx = threadIdx.x, ty = threadIdx.y; // (32,8)
    const float* xp = x + ((size_t)b * C_ + c0) * S_ + s0;
#pragma unroll
    for (int i = 0; i < 4; i++)
        tile[ty + i * 8][tx] = xp[(size_t)(ty + i * 8) * S_ + tx];
    __syncthreads();
    unsigned short* op = xT + ((size_t)b * S_ + s0) * C_ + c0;
#pragma unroll
    for (int i = 0; i < 4; i++)
        op[(size_t)(ty + i * 8) * C_ + tx] = f2b(tile[tx][ty + i * 8]);
}

// ---------- prep: f32 -> bf16 (vector x4) ----------
__global__ void convert_f32_bf16(const float* __restrict__ src, unsigned short* __restrict__ dst, int n4) {
    int i = blockIdx.x * blockDim.x + threadIdx.x;
    if (i < n4) {
        float4 v = ((const float4*)src)[i];
        ((ushort4*)dst)[i] = make_ushort4(f2b(v.x), f2b(v.y), f2b(v.z), f2b(v.w));
    }
}

// ---------- zero fill ----------
__global__ void zero_f32(float* __restrict__ p, int n) {
    int i = blockIdx.x * blockDim.x + threadIdx.x;
    if (i < n) p[i] = 0.0f;
}

// ---------- GEMM: C[m,n] = A[m,:] . Wt[n,:] + bias[n] ----------
// A: MxK bf16 row-major (K contig), Wt: NxK bf16 row-major. K=512.
// TRANS_OUT=false: store bf16 y[m*N + n]
// TRANS_OUT=true : store f32 out[(b*512+n)*1024 + s], m = b*1024+s  (N must be 512)
template <bool TRANS_OUT>
__global__ __launch_bounds__(256) void gemm_bf16(
    const unsigned short* __restrict__ A,
    const unsigned short* __restrict__ Wt,
    const float* __restrict__ bias,
    void* __restrict__ Cout,
    int N)
{
    const int K = 512;
    __shared__ __align__(16) unsigned short As[128 * 40]; // 80B row stride (pad)
    __shared__ __align__(16) unsigned short Bs[128 * 40];
    int m0 = blockIdx.x * 128;
    int n0 = blockIdx.y * 128;
    int tid = threadIdx.x;
    int lane = tid & 63, wid = tid >> 6;
    int wm = (wid >> 1) * 64, wn = (wid & 1) * 64;
    int quad = lane >> 4, l16 = lane & 15;

    f32x4 acc[4][4] = {};

    for (int kt = 0; kt < K; kt += 32) {
        __syncthreads();
#pragma unroll
        for (int r = 0; r < 2; r++) {
            int ch = tid + r * 256;       // 512 chunks of 16B per tile
            int m = ch >> 2, kc = ch & 3;
            *(uint4*)(&As[m * 40 + kc * 8]) = *(const uint4*)(&A[(size_t)(m0 + m) * K + kt + kc * 8]);
            *(uint4*)(&Bs[m * 40 + kc * 8]) = *(const uint4*)(&Wt[(size_t)(n0 + m) * K + kt + kc * 8]);
        }
        __syncthreads();
        bf16x8 af[4], bf[4];
#pragma unroll
        for (int t = 0; t < 4; t++) {
            af[t] = *(const bf16x8*)(&As[(wm + t * 16 + l16) * 40 + quad * 8]);
            bf[t] = *(const bf16x8*)(&Bs[(wn + t * 16 + l16) * 40 + quad * 8]);
        }
#pragma unroll
        for (int mt = 0; mt < 4; mt++)
#pragma unroll
            for (int nt = 0; nt < 4; nt++)
                acc[mt][nt] = __builtin_amdgcn_mfma_f32_16x16x32_bf16(af[mt], bf[nt], acc[mt][nt], 0, 0, 0);
    }

#pragma unroll
    for (int mt = 0; mt < 4; mt++) {
#pragma unroll
        for (int nt = 0; nt < 4; nt++) {
            int n = n0 + wn + nt * 16 + l16;
            float bv = bias[n];
            int mbase = m0 + wm + mt * 16 + quad * 4;
            if (!TRANS_OUT) {
                unsigned short* Y = (unsigned short*)Cout;
#pragma unroll
                for (int r = 0; r < 4; r++)
                    Y[(size_t)(mbase + r) * N + n] = f2b(acc[mt][nt][r] + bv);
            } else {
                float* Z = (float*)Cout;
                int b = mbase >> 10;
                int s = mbase & 1023;
                float4 v = make_float4(acc[mt][nt][0] + bv, acc[mt][nt][1] + bv,
                                       acc[mt][nt][2] + bv, acc[mt][nt][3] + bv);
                *(float4*)(&Z[((size_t)(b * 512 + n)) * 1024 + s]) = v;
            }
        }
    }
}

// shift tables per quarter q = c>>7:
// x1: dw = {-1,+1,0,0}[q], dh = {0,0,-1,+1}[q]   (channels [0,512) of y)
// x2: dh = {-1,+1,0,0}[q], dw = {0,0,-1,+1}[q]   (channels [512,1024))
// x3: no shift                                    (channels [1024,1536))

// ---------- a[b,c] = sum_{w,h} (x1+x2+x3) ----------
__global__ void asum_kernel(const unsigned short* __restrict__ y, float* __restrict__ a) {
    int b = blockIdx.y;
    int w0 = blockIdx.x * 2;
    int t = threadIdx.x;
    int c = t * 2;
    int q = c >> 7;
    int dw1 = (q == 0) ? -1 : (q == 1) ? 1 : 0;
    int dh1 = (q == 2) ? -1 : (q == 3) ? 1 : 0;
    int dh2 = (q == 0) ? -1 : (q == 1) ? 1 : 0;
    int dw2 = (q == 2) ? -1 : (q == 3) ? 1 : 0;
    float s0 = 0.f, s1 = 0.f;
    size_t base = (size_t)b * S_;
    for (int p = 0; p < 64; p++) {
        int w = w0 + (p >> 5);
        int h = p & 31;
        int w1i = min(max(w + dw1, 0), 31), h1i = min(max(h + dh1, 0), 31);
        int w2i = min(max(w + dw2, 0), 31), h2i = min(max(h + dh2, 0), 31);
        unsigned int v1 = *(const unsigned int*)&y[(base + w1i * 32 + h1i) * N1 + c];
        unsigned int v2 = *(const unsigned int*)&y[(base + w2i * 32 + h2i) * N1 + 512 + c];
        unsigned int v3 = *(const unsigned int*)&y[(base + w * 32 + h) * N1 + 1024 + c];
        s0 += b2f(v1) + b2f(v2) + b2f(v3);
        s1 += b2f(v1 >> 16) + b2f(v2 >> 16) + b2f(v3 >> 16);
    }
    atomicAdd(&a[b * 512 + c], s0);
    atomicAdd(&a[b * 512 + c + 1], s1);
}

// ---------- gating MLP, wave-per-output-row ----------
// layer1: h[b*512+o] = gelu(dot(a[b,:], wa[o,:]) + ba[o])
__global__ __launch_bounds__(256) void mlp_layer1(
    const float* __restrict__ a, const float* __restrict__ wa,
    const float* __restrict__ ba, float* __restrict__ h)
{
    int gw = (blockIdx.x * 256 + threadIdx.x) >> 6; // global wave id, 8192 total
    int lane = threadIdx.x & 63;
    int b = gw >> 9;
    int o = gw & 511;
    const float4* wr = (const float4*)(wa + (size_t)o * 512);
    const float4* ar = (const float4*)(a + (size_t)b * 512);
    float4 w0 = wr[lane * 2], w1 = wr[lane * 2 + 1];
    float4 a0 = ar[lane * 2], a1 = ar[lane * 2 + 1];
    float dot = w0.x * a0.x + w0.y * a0.y + w0.z * a0.z + w0.w * a0.w
              + w1.x * a1.x + w1.y * a1.y + w1.z * a1.z + w1.w * a1.w;
#pragma unroll
    for (int off = 32; off; off >>= 1) dot += __shfl_down(dot, off);
    if (lane == 0) {
        float v = dot + ba[o];
        h[(size_t)b * 512 + o] = 0.5f * v * (1.0f + erff(v * 0.7071067811865475f));
    }
}

// layer2: hat[b*1536+o] = dot(h[b,:], wb[o,:]) + bb[o]
__global__ __launch_bounds__(256) void mlp_layer2(
    const float* __restrict__ h, const float* __restrict__ wb,
    const float* __restrict__ bb, float* __restrict__ hat)
{
    int gw = (blockIdx.x * 256 + threadIdx.x) >> 6; // 24576 total
    int lane = threadIdx.x & 63;
    int b = gw / 1536;
    int o = gw - b * 1536;
    const float4* wr = (const float4*)(wb + (size_t)o * 512);
    const float4* hr = (const float4*)(h + (size_t)b * 512);
    float4 w0 = wr[lane * 2], w1 = wr[lane * 2 + 1];
    float4 h0 = hr[lane * 2], h1 = hr[lane * 2 + 1];
    float dot = w0.x * h0.x + w0.y * h0.y + w0.z * h0.z + w0.w * h0.w
              + w1.x * h1.x + w1.y * h1.y + w1.z * h1.z + w1.w * h1.w;
#pragma unroll
    for (int off = 32; off; off >>= 1) dot += __shfl_down(dot, off);
    if (lane == 0)
        hat[(size_t)b * 1536 + o] = dot + bb[o];
}

// softmax over the 3 groups: g[b,j,c] = softmax_j(hat[b, j*512+c])
__global__ __launch_bounds__(256) void softmax_gate(
    const float* __restrict__ hat, float* __restrict__ g)
{
    int i = blockIdx.x * 256 + threadIdx.x; // 8192
    int b = i >> 9, c = i & 511;
    float h0 = hat[(size_t)b * 1536 + c];
    float h1 = hat[(size_t)b * 1536 + 512 + c];
    float h2 = hat[(size_t)b * 1536 + 1024 + c];
    float mx = fmaxf(h0, fmaxf(h1, h2));
    float e0 = __expf(h0 - mx), e1 = __expf(h1 - mx), e2 = __expf(h2 - mx);
    float inv = 1.0f / (e0 + e1 + e2);
    g[(b * 3 + 0) * 512 + c] = e0 * inv;
    g[(b * 3 + 1) * 512 + c] = e1 * inv;
    g[(b * 3 + 2) * 512 + c] = e2 * inv;
}

// ---------- out[b,s,c] = g0*x1 + g1*x2 + g2*x3 (bf16) ----------
__global__ void combine_kernel(const unsigned short* __restrict__ y,
                               const float* __restrict__ g,
                               unsigned short* __restrict__ outT)
{
    int b = blockIdx.y;
    int w = blockIdx.x;
    int t = threadIdx.x;
    int c = t * 2;
    int q = c >> 7;
    int dw1 = (q == 0) ? -1 : (q == 1) ? 1 : 0;
    int dh1 = (q == 2) ? -1 : (q == 3) ? 1 : 0;
    int dh2 = (q == 0) ? -1 : (q == 1) ? 1 : 0;
    int dw2 = (q == 2) ? -1 : (q == 3) ? 1 : 0;
    float g00 = g[(b * 3 + 0) * 512 + c], g01 = g[(b * 3 + 0) * 512 + c + 1];
    float g10 = g[(b * 3 + 1) * 512 + c], g11 = g[(b * 3 + 1) * 512 + c + 1];
    float g20 = g[(b * 3 + 2) * 512 + c], g21 = g[(b * 3 + 2) * 512 + c + 1];
    int w1i = min(max(w + dw1, 0), 31);
    int w2i = min(max(w + dw2, 0), 31);
    size_t base = (size_t)b * S_;
    for (int h = 0; h < 32; h++) {
        int h1i = min(max(h + dh1, 0), 31);
        int h2i = min(max(h + dh2, 0), 31);
        unsigned int v1 = *(const unsigned int*)&y[(base + w1i * 32 + h1i) * N1 + c];
        unsigned int v2 = *(const unsigned int*)&y[(base + w2i * 32 + h2i) * N1 + 512 + c];
        unsigned int v3 = *(const unsigned int*)&y[(base + w * 32 + h) * N1 + 1024 + c];
        float o0 = g00 * b2f(v1) + g10 * b2f(v2) + g20 * b2f(v3);
        float o1 = g01 * b2f(v1 >> 16) + g11 * b2f(v2 >> 16) + g21 * b2f(v3 >> 16);
        unsigned int ov = (unsigned int)f2b(o0) | ((unsigned int)f2b(o1) << 16);
        *(unsigned int*)&outT[(base + w * 32 + h) * 512 + c] = ov;
    }
}

extern "C" void kernel_launch(void* const* d_in, const int* in_sizes, int n_in,
                              void* d_out, int out_size, void* d_ws, size_t ws_size,
                              hipStream_t stream) {
    const float* x  = (const float*)d_in[0];
    const float* w1 = (const float*)d_in[1];
    const float* b1 = (const float*)d_in[2];
    const float* wa = (const float*)d_in[3];
    const float* ba = (const float*)d_in[4];
    const float* wb = (const float*)d_in[5];
    const float* bb = (const float*)d_in[6];
    const float* w2 = (const float*)d_in[7];
    const float* b2 = (const float*)d_in[8];
    float* out = (float*)d_out;

    char* ws = (char*)d_ws;
    unsigned short* xT   = (unsigned short*)(ws);              // 16 MB: (B,S,C) bf16
    unsigned short* w1b  = (unsigned short*)(ws + 16777216);   // 1.5 MB
    unsigned short* w2b  = (unsigned short*)(ws + 18350080);   // 0.5 MB
    unsigned short* y    = (unsigned short*)(ws + 18874368);   // 48 MB: (B,S,3C) bf16
    float* a_buf         = (float*)(ws + 69206016);            // 32 KB
    float* g_buf         = (float*)(ws + 69238784);            // 96 KB
    float* h_buf         = (float*)(ws + 69337088);            // 32 KB: (16,512) f32
    float* hat_buf       = (float*)(ws + 69369856);            // 96 KB: (16,1536) f32
    unsigned short* outT = (unsigned short*)(ws + 69468160);   // 16 MB: (B,S,C) bf16

    transpose_convert_x<<<dim3(32, 16, 16), dim3(32, 8), 0, stream>>>(x, xT);
    convert_f32_bf16<<<dim3(768), dim3(256), 0, stream>>>(w1, w1b, 196608);
    convert_f32_bf16<<<dim3(256), dim3(256), 0, stream>>>(w2, w2b, 65536);
    gemm_bf16<false><<<dim3(128, 12), dim3(256), 0, stream>>>(xT, w1b, b1, (void*)y, 1536);
    zero_f32<<<dim3(32), dim3(256), 0, stream>>>(a_buf, 8192);
    asum_kernel<<<dim3(16, 16), dim3(256), 0, stream>>>(y, a_buf);
    mlp_layer1<<<dim3(2048), dim3(256), 0, stream>>>(a_buf, wa, ba, h_buf);
    mlp_layer2<<<dim3(6144), dim3(256), 0, stream>>>(h_buf, wb, bb, hat_buf);
    softmax_gate<<<dim3(32), dim3(256), 0, stream>>>(hat_buf, g_buf);
    combine_kernel<<<dim3(32, 16), dim3(256), 0, stream>>>(y, g_buf, outT);
    gemm_bf16<true><<<dim3(128, 4), dim3(256), 0, stream>>>(outT, w2b, b2, (void*)out, 512);
}

// Round 4
// 193.445 us; speedup vs baseline: 1.7055x; 1.1243x over previous
//
#include <hip/hip_runtime.h>
#include <stdint.h>

typedef __bf16 bf16x8 __attribute__((ext_vector_type(8)));
typedef float f32x4 __attribute__((ext_vector_type(4)));

#define B_ 16
#define C_ 512
#define S_ 1024   // W*H = 32*32
#define N1 1536   // 3C

// ---------- bf16 helpers (manual RNE) ----------
__device__ inline unsigned short f2b(float f) {
    unsigned int u = __builtin_bit_cast(unsigned int, f);
    unsigned int lsb = (u >> 16) & 1u;
    u += 0x7fffu + lsb;
    return (unsigned short)(u >> 16);
}
__device__ inline float b2f(unsigned int s) {
    unsigned int u = (s & 0xffffu) << 16;
    return __builtin_bit_cast(float, u);
}

// async global->LDS, 16B per lane. LDS dest must be wave-uniform base + lane*16.
__device__ inline void gl_lds16(const unsigned short* g, unsigned short* l) {
    __builtin_amdgcn_global_load_lds(
        (const __attribute__((address_space(1))) void*)(g),
        (__attribute__((address_space(3))) void*)(l),
        16, 0, 0);
}

// ---------- prep: x (B,C,S) f32 -> xT (B,S,C) bf16 (R2-proven version) ----------
__global__ void transpose_convert_x(const float* __restrict__ x, unsigned short* __restrict__ xT) {
    __shared__ float tile[32][33];
    int b = blockIdx.z;
    int c0 = blockIdx.y * 32;
    int s0 = blockIdx.x * 32;
    int tx = threadIdx.x, ty = threadIdx.y; // (32,8)
    const float* xp = x + ((size_t)b * C_ + c0) * S_ + s0;
#pragma unroll
    for (int i = 0; i < 4; i++)
        tile[ty + i * 8][tx] = xp[(size_t)(ty + i * 8) * S_ + tx];
    __syncthreads();
    unsigned short* op = xT + ((size_t)b * S_ + s0) * C_ + c0;
#pragma unroll
    for (int i = 0; i < 4; i++)
        op[(size_t)(ty + i * 8) * C_ + tx] = f2b(tile[tx][ty + i * 8]);
}

// ---------- prep: convert w1,w2 to bf16 + zero the 5 sum planes ----------
// work items are float4-granular: w1 = 196608, w2 = 65536, sums = 30720
__global__ __launch_bounds__(256) void misc_prep(
    const float* __restrict__ w1, const float* __restrict__ w2,
    unsigned short* __restrict__ w1b, unsigned short* __restrict__ w2b,
    float* __restrict__ sums)
{
    int i = blockIdx.x * 256 + threadIdx.x;
    if (i < 196608) {
        float4 v = ((const float4*)w1)[i];
        ((ushort4*)w1b)[i] = make_ushort4(f2b(v.x), f2b(v.y), f2b(v.z), f2b(v.w));
    } else if (i < 262144) {
        int j = i - 196608;
        float4 v = ((const float4*)w2)[j];
        ((ushort4*)w2b)[j] = make_ushort4(f2b(v.x), f2b(v.y), f2b(v.z), f2b(v.w));
    } else if (i < 292864) {
        int j = i - 262144;
        ((float4*)sums)[j] = make_float4(0.f, 0.f, 0.f, 0.f);
    }
}

// ---------- GEMM: C[m,n] = A[m,:] . Wt[n,:] + bias[n], K=512 ----------
// m97 structure: global_load_lds width-16 staging, unpadded 64B LDS rows.
// DO_SUMS: accumulate T/H0/H31/C0/C31 planes (16x1536 each) for the gating a-sum.
// TRANS_OUT: store f32 out[(b*512+n)*1024 + s], m = b*1024+s (N=512).
template <bool TRANS_OUT, bool DO_SUMS>
__global__ __launch_bounds__(256) void gemm_bf16(
    const unsigned short* __restrict__ A,
    const unsigned short* __restrict__ Wt,
    const float* __restrict__ bias,
    void* __restrict__ Cout, int N,
    float* __restrict__ Tsum, float* __restrict__ H0, float* __restrict__ H31,
    float* __restrict__ C0, float* __restrict__ C31)
{
    const int K = 512;
    __shared__ __align__(16) unsigned short As[128 * 32]; // 8 KB, 64B rows
    __shared__ __align__(16) unsigned short Bs[128 * 32];
    int m0 = blockIdx.x * 128;
    int n0 = blockIdx.y * 128;
    int tid = threadIdx.x;
    int lane = tid & 63, wid = tid >> 6;
    int wm = (wid >> 1) * 64, wn = (wid & 1) * 64;
    int quad = lane >> 4, l16 = lane & 15;
    int ch0 = wid * 128 + lane;
    const unsigned short* Ab = A + (size_t)m0 * K;
    const unsigned short* Bb = Wt + (size_t)n0 * K;

    f32x4 acc[4][4] = {};

    for (int kt = 0; kt < K; kt += 32) {
        __syncthreads();
#pragma unroll
        for (int i = 0; i < 2; i++) {
            int ch = ch0 + i * 64;
            int m = ch >> 2, kc = ch & 3;
            size_t go = (size_t)m * K + kt + kc * 8;
            gl_lds16(Ab + go, &As[ch * 8]);
            gl_lds16(Bb + go, &Bs[ch * 8]);
        }
        __syncthreads();
        bf16x8 af[4], bfr[4];
#pragma unroll
        for (int t = 0; t < 4; t++) {
            af[t]  = *(const bf16x8*)&As[(wm + t * 16 + l16) * 32 + quad * 8];
            bfr[t] = *(const bf16x8*)&Bs[(wn + t * 16 + l16) * 32 + quad * 8];
        }
#pragma unroll
        for (int mt = 0; mt < 4; mt++)
#pragma unroll
            for (int nt = 0; nt < 4; nt++)
                acc[mt][nt] = __builtin_amdgcn_mfma_f32_16x16x32_bf16(af[mt], bfr[nt], acc[mt][nt], 0, 0, 0);
    }

    // ---- write output ----
#pragma unroll
    for (int mt = 0; mt < 4; mt++) {
#pragma unroll
        for (int nt = 0; nt < 4; nt++) {
            int n = n0 + wn + nt * 16 + l16;
            float bv = bias[n];
            int mbase = m0 + wm + mt * 16 + quad * 4;
            if (!TRANS_OUT) {
                unsigned short* Y = (unsigned short*)Cout;
#pragma unroll
                for (int r = 0; r < 4; r++)
                    Y[(size_t)(mbase + r) * N + n] = f2b(acc[mt][nt][r] + bv);
            } else {
                float* Z = (float*)Cout;
                int b = mbase >> 10;
                int s = mbase & 1023;
                float4 v = make_float4(acc[mt][nt][0] + bv, acc[mt][nt][1] + bv,
                                       acc[mt][nt][2] + bv, acc[mt][nt][3] + bv);
                *(float4*)(&Z[((size_t)(b * 512 + n)) * 1024 + s]) = v;
            }
        }
    }

    // ---- fused a-sum accumulators ----
    // m_local = wm + mt*16 + quad*4 + r; h = m_local&31; w = wlo + (m_local>>5)
    if (DO_SUMS) {
        int b = m0 >> 10;
        int wlo = (m0 & 1023) >> 5; // first of 4 w-rows in this block
#pragma unroll
        for (int nt = 0; nt < 4; nt++) {
            int n = n0 + wn + nt * 16 + l16;
            float bv = bias[n];
            // total over this wave's 64 m's
            float tT = 0.f;
#pragma unroll
            for (int mt = 0; mt < 4; mt++)
#pragma unroll
                for (int r = 0; r < 4; r++) tT += acc[mt][nt][r] + bv;
            tT += __shfl_xor(tT, 16);
            tT += __shfl_xor(tT, 32);
            if (quad == 0) {
                atomicAdd(&Tsum[b * 1536 + n], tT);
                // h==0 rows: m_local = wm+{0,32} -> (mt 0,2, quad0, r0)
                float th0 = acc[0][nt][0] + acc[2][nt][0] + 2.f * bv;
                atomicAdd(&H0[b * 1536 + n], th0);
            }
            if (quad == 3) {
                // h==31 rows: m_local = wm+{31,63} -> (mt 1,3, quad3, r3)
                float th31 = acc[1][nt][3] + acc[3][nt][3] + 2.f * bv;
                atomicAdd(&H31[b * 1536 + n], th31);
            }
            if (wlo == 0 && wm == 0) { // w==0 slice: m_local < 32 -> mt 0,1
                float tc = 0.f;
#pragma unroll
                for (int mt = 0; mt < 2; mt++)
#pragma unroll
                    for (int r = 0; r < 4; r++) tc += acc[mt][nt][r] + bv;
                tc += __shfl_xor(tc, 16);
                tc += __shfl_xor(tc, 32);
                if (quad == 0) atomicAdd(&C0[b * 1536 + n], tc);
            }
            if (wlo == 28 && wm == 64) { // w==31 slice: m_local >= 96 -> mt 2,3
                float tc = 0.f;
#pragma unroll
                for (int mt = 2; mt < 4; mt++)
#pragma unroll
                    for (int r = 0; r < 4; r++) tc += acc[mt][nt][r] + bv;
                tc += __shfl_xor(tc, 16);
                tc += __shfl_xor(tc, 32);
                if (quad == 0) atomicAdd(&C31[b * 1536 + n], tc);
            }
        }
    }
}

// ---------- layer1: reconstruct a[b,:] from sum planes, then wave-dot ----------
// a[b,c]: q=c>>7, sgn=(q&1)?-1:+1,
//   e = (q<2) ? (C0-C31)[n1]+(H0-H31)[n2] : (H0-H31)[n1]+(C0-C31)[n2]
//   a = T[n1]+T[n2]+T[n3] + sgn*e       (n1=c, n2=512+c, n3=1024+c)
__global__ __launch_bounds__(256) void mlp_layer1(
    const float* __restrict__ sums, const float* __restrict__ wa,
    const float* __restrict__ ba, float* __restrict__ h)
{
    __shared__ float sa[512];
    int b = blockIdx.x >> 7;
    int t = threadIdx.x;
    const float* Tp   = sums;
    const float* H0p  = sums + 24576;
    const float* H31p = sums + 49152;
    const float* C0p  = sums + 73728;
    const float* C31p = sums + 98304;
#pragma unroll
    for (int j = 0; j < 2; j++) {
        int c = t + j * 256;
        int q = c >> 7;
        int n1 = b * 1536 + c;
        float t123 = Tp[n1] + Tp[n1 + 512] + Tp[n1 + 1024];
        float sC1 = C0p[n1] - C31p[n1];
        float sH1 = H0p[n1] - H31p[n1];
        float sC2 = C0p[n1 + 512] - C31p[n1 + 512];
        float sH2 = H0p[n1 + 512] - H31p[n1 + 512];
        float e = (q < 2) ? (sC1 + sH2) : (sH1 + sC2);
        sa[c] = t123 + ((q & 1) ? -e : e);
    }
    __syncthreads();
    int lane = t & 63, wid = t >> 6;
    int o = (blockIdx.x & 127) * 4 + wid;
    const float4* wr = (const float4*)(wa + (size_t)o * 512);
    float4 w0 = wr[lane * 2], w1v = wr[lane * 2 + 1];
    float4 a0 = ((const float4*)sa)[lane * 2], a1 = ((const float4*)sa)[lane * 2 + 1];
    float dot = w0.x * a0.x + w0.y * a0.y + w0.z * a0.z + w0.w * a0.w
              + w1v.x * a1.x + w1v.y * a1.y + w1v.z * a1.z + w1v.w * a1.w;
#pragma unroll
    for (int off = 32; off; off >>= 1) dot += __shfl_down(dot, off);
    if (lane == 0) {
        float v = dot + ba[o];
        h[b * 512 + o] = 0.5f * v * (1.0f + erff(v * 0.7071067811865475f));
    }
}

// ---------- layer2: hat[b*1536+o] = dot(h[b,:], wb[o,:]) + bb[o] ----------
__global__ __launch_bounds__(256) void mlp_layer2(
    const float* __restrict__ h, const float* __restrict__ wb,
    const float* __restrict__ bb, float* __restrict__ hat)
{
    int gw = (blockIdx.x * 256 + threadIdx.x) >> 6; // 24576 waves
    int lane = threadIdx.x & 63;
    int b = gw / 1536;
    int o = gw - b * 1536;
    const float4* wr = (const float4*)(wb + (size_t)o * 512);
    const float4* hr = (const float4*)(h + (size_t)b * 512);
    float4 w0 = wr[lane * 2], w1 = wr[lane * 2 + 1];
    float4 h0 = hr[lane * 2], h1 = hr[lane * 2 + 1];
    float dot = w0.x * h0.x + w0.y * h0.y + w0.z * h0.z + w0.w * h0.w
              + w1.x * h1.x + w1.y * h1.y + w1.z * h1.z + w1.w * h1.w;
#pragma unroll
    for (int off = 32; off; off >>= 1) dot += __shfl_down(dot, off);
    if (lane == 0)
        hat[(size_t)b * 1536 + o] = dot + bb[o];
}

// ---------- combine (softmax inline): out[b,s,c] = sum_j g_j * x_j (bf16) ----------
__global__ __launch_bounds__(256) void combine_softmax(
    const unsigned short* __restrict__ y, const float* __restrict__ hat,
    unsigned short* __restrict__ outT)
{
    int b = blockIdx.y;
    int t = threadIdx.x;
    int w = blockIdx.x * 4 + (t >> 6);
    int c8 = (t & 63) * 8;
    int q = c8 >> 7;
    int dw1 = (q == 0) ? -1 : (q == 1) ? 1 : 0;
    int dh1 = (q == 2) ? -1 : (q == 3) ? 1 : 0;
    int dh2 = (q == 0) ? -1 : (q == 1) ? 1 : 0;
    int dw2 = (q == 2) ? -1 : (q == 3) ? 1 : 0;
    float g0[8], g1[8], g2[8];
#pragma unroll
    for (int j = 0; j < 8; j++) {
        int c = c8 + j;
        float h0 = hat[b * 1536 + c];
        float h1 = hat[b * 1536 + 512 + c];
        float h2 = hat[b * 1536 + 1024 + c];
        float mx = fmaxf(h0, fmaxf(h1, h2));
        float e0 = __expf(h0 - mx), e1 = __expf(h1 - mx), e2 = __expf(h2 - mx);
        float inv = 1.0f / (e0 + e1 + e2);
        g0[j] = e0 * inv; g1[j] = e1 * inv; g2[j] = e2 * inv;
    }
    int w1i = min(max(w + dw1, 0), 31);
    int w2i = min(max(w + dw2, 0), 31);
    size_t base = (size_t)b * S_;
    for (int h = 0; h < 32; h++) {
        int h1i = min(max(h + dh1, 0), 31);
        int h2i = min(max(h + dh2, 0), 31);
        uint4 u1 = *(const uint4*)&y[(base + w1i * 32 + h1i) * N1 + c8];
        uint4 u2 = *(const uint4*)&y[(base + w2i * 32 + h2i) * N1 + 512 + c8];
        uint4 u3 = *(const uint4*)&y[(base + w * 32 + h) * N1 + 1024 + c8];
        unsigned int p[4];
        const unsigned int* a1 = &u1.x;
        const unsigned int* a2 = &u2.x;
        const unsigned int* a3 = &u3.x;
#pragma unroll
        for (int k = 0; k < 4; k++) {
            int j = k * 2;
            float lo = g0[j] * b2f(a1[k]) + g1[j] * b2f(a2[k]) + g2[j] * b2f(a3[k]);
            float hi = g0[j + 1] * b2f(a1[k] >> 16) + g1[j + 1] * b2f(a2[k] >> 16) + g2[j + 1] * b2f(a3[k] >> 16);
            p[k] = (unsigned int)f2b(lo) | ((unsigned int)f2b(hi) << 16);
        }
        *(uint4*)&outT[(base + w * 32 + h) * 512 + c8] = make_uint4(p[0], p[1], p[2], p[3]);
    }
}

extern "C" void kernel_launch(void* const* d_in, const int* in_sizes, int n_in,
                              void* d_out, int out_size, void* d_ws, size_t ws_size,
                              hipStream_t stream) {
    const float* x  = (const float*)d_in[0];
    const float* w1 = (const float*)d_in[1];
    const float* b1 = (const float*)d_in[2];
    const float* wa = (const float*)d_in[3];
    const float* ba = (const float*)d_in[4];
    const float* wb = (const float*)d_in[5];
    const float* bb = (const float*)d_in[6];
    const float* w2 = (const float*)d_in[7];
    const float* b2 = (const float*)d_in[8];
    float* out = (float*)d_out;

    char* ws = (char*)d_ws;
    unsigned short* xT   = (unsigned short*)(ws);              // 16 MB (dead after gemm1)
    unsigned short* outT = (unsigned short*)(ws);              // aliases xT (combine runs after gemm1)
    unsigned short* w1b  = (unsigned short*)(ws + 16777216);   // 1.5 MB
    unsigned short* w2b  = (unsigned short*)(ws + 18350080);   // 0.5 MB
    unsigned short* y    = (unsigned short*)(ws + 18874368);   // 48 MB: (B,S,3C) bf16
    float* sums          = (float*)(ws + 69206016);            // 5 x 96 KB: T,H0,H31,C0,C31
    float* h_buf         = (float*)(ws + 69697536);            // 32 KB
    float* hat_buf       = (float*)(ws + 69730304);            // 96 KB

    float* Tsum = sums;
    float* H0   = sums + 24576;
    float* H31  = sums + 49152;
    float* C0   = sums + 73728;
    float* C31  = sums + 98304;

    transpose_convert_x<<<dim3(32, 16, 16), dim3(32, 8), 0, stream>>>(x, xT);
    misc_prep<<<dim3(1144), dim3(256), 0, stream>>>(w1, w2, w1b, w2b, sums);
    gemm_bf16<false, true><<<dim3(128, 12), dim3(256), 0, stream>>>(
        xT, w1b, b1, (void*)y, 1536, Tsum, H0, H31, C0, C31);
    mlp_layer1<<<dim3(2048), dim3(256), 0, stream>>>(sums, wa, ba, h_buf);
    mlp_layer2<<<dim3(6144), dim3(256), 0, stream>>>(h_buf, wb, bb, hat_buf);
    combine_softmax<<<dim3(8, 16), dim3(256), 0, stream>>>(y, hat_buf, outT);
    gemm_bf16<true, false><<<dim3(128, 4), dim3(256), 0, stream>>>(
        outT, w2b, b2, (void*)out, 512, nullptr, nullptr, nullptr, nullptr, nullptr);
}